// Round 6
// baseline (389.648 us; speedup 1.0000x reference)
//
#include <hip/hip_runtime.h>
#include <stdint.h>

#define SEQ  20
#define H1   128
#define H2   256
#define NCLS 100000

#define AQ  __ATOMIC_ACQUIRE
#define RL  __ATOMIC_RELEASE
#define RX  __ATOMIC_RELAXED
#define AG  __HIP_MEMORY_SCOPE_AGENT

// Opaque touch: forbids rematerializing weight loads inside serial loops
// (values may live in AGPRs on gfx950's unified file -- that's fine).
#define KEEPF4(v) asm volatile("" : "+v"((v).x), "+v"((v).y), "+v"((v).z), "+v"((v).w))

__device__ __forceinline__ float sigm(float x) { return 1.0f / (1.0f + __expf(-x)); }
__device__ __forceinline__ float tanhfast(float x) {
    float e = __expf(-2.0f * fabsf(x));
    float t = (1.0f - e) / (1.0f + e);
    return copysignf(t, x);
}

// ---------------------------------------------------------------------------
// Layer-1 LSTM: one block per direction, 1024 threads, ZERO atomics.
// comb written with plain stores; the kernel boundary publishes it to k_l2.
// ---------------------------------------------------------------------------
__global__ __launch_bounds__(1024, 1) void k_l1(
    const float* __restrict__ x,
    const float* __restrict__ h0f, const float* __restrict__ c0f,
    const float* __restrict__ h0b, const float* __restrict__ c0b,
    const float* __restrict__ WihF, const float* __restrict__ WhhF,
    const float* __restrict__ bihF, const float* __restrict__ bhhF,
    const float* __restrict__ WihB, const float* __restrict__ WhhB,
    const float* __restrict__ bihB, const float* __restrict__ bhhB,
    float* __restrict__ comb)      // [SEQ][H2]
{
    const int dir = blockIdx.x;
    const float* Wih = dir ? WihB : WihF;
    const float* Whh = dir ? WhhB : WhhF;
    const float* bih = dir ? bihB : bihF;
    const float* bhh = dir ? bhhB : bhhF;
    const float* h0  = dir ? h0b  : h0f;
    const float* c0  = dir ? c0b  : c0f;

    __shared__ __align__(16) float smem[16032];
    float* xs      = smem;                    // 2560
    float* hcur    = xs + 2560;               // 128
    float* biasL   = hcur + 128;              // 512
    float* gxs     = biasL + 512;             // 512*21 = 10752
    float* partial = gxs + 10752;             // 4*520 = 2080

    const int tid = threadIdx.x;

    for (int i = tid; i < SEQ * H1; i += 1024) xs[i] = x[i];
    if (tid < 4 * H1) biasL[tid] = bih[tid] + bhh[tid];
    if (tid < H1) hcur[tid] = h0[tid];
    float cregA = 0.f, cregB = 0.f;
    if (tid < 64) { cregA = c0[tid]; cregB = c0[tid + 64]; }

    // ---- prologue: thread = (row pr, half ph); Wih slice in regs ----
    const int pr = tid >> 1, ph = tid & 1;
    {
        float4 wf[16];
        const float4* p = (const float4*)(Wih + pr * H1 + ph * 64);
#pragma unroll
        for (int j = 0; j < 16; ++j) { wf[j] = p[j]; KEEPF4(wf[j]); }
        __syncthreads();
        for (int t = 0; t < SEQ; ++t) {
            const int tx = dir ? (SEQ - 1 - t) : t;
            const float4* xp = (const float4*)(xs + tx * H1 + ph * 64);
            float a = 0.f;
#pragma unroll
            for (int j = 0; j < 16; ++j) {
                float4 v = xp[j];
                a += wf[j].x * v.x + wf[j].y * v.y + wf[j].z * v.z + wf[j].w * v.w;
            }
            a += __shfl_xor(a, 1);
            if (ph == 0) gxs[pr * 21 + t] = a + biasL[pr];
        }
    }

    // ---- recurrence weights -> registers ----
    const int cg = tid >> 8, r0 = (tid & 255) * 2;
    float4 wa[8], wb[8];
    {
        const float4* pa = (const float4*)(Whh + r0 * H1 + cg * 32);
        const float4* pb = (const float4*)(Whh + (r0 + 1) * H1 + cg * 32);
#pragma unroll
        for (int j = 0; j < 8; ++j) {
            wa[j] = pa[j]; KEEPF4(wa[j]);
            wb[j] = pb[j]; KEEPF4(wb[j]);
        }
    }
    __syncthreads();

    for (int t = 0; t < SEQ; ++t) {
        const float4* hp = (const float4*)(hcur + cg * 32);   // broadcast
        float a0 = 0.f, a1 = 0.f;
#pragma unroll
        for (int j = 0; j < 8; ++j) {
            float4 v = hp[j];
            a0 += wa[j].x * v.x + wa[j].y * v.y + wa[j].z * v.z + wa[j].w * v.w;
            a1 += wb[j].x * v.x + wb[j].y * v.y + wb[j].z * v.z + wb[j].w * v.w;
        }
        *(float2*)(partial + cg * 520 + r0) = make_float2(a0, a1);
        __syncthreads();
        if (tid < 64) {                       // finish 2 cells each
            const int c = tid;
            float s0[4], s1[4];
#pragma unroll
            for (int g = 0; g < 4; ++g) {
                float accA = gxs[(g * H1 + c) * 21 + t];
                float accB = gxs[(g * H1 + c + 64) * 21 + t];
#pragma unroll
                for (int q = 0; q < 4; ++q) {
                    accA += partial[q * 520 + g * H1 + c];
                    accB += partial[q * 520 + g * H1 + c + 64];
                }
                s0[g] = accA; s1[g] = accB;
            }
            float cnA = sigm(s0[1]) * cregA + sigm(s0[0]) * tanhfast(s0[2]);
            float cnB = sigm(s1[1]) * cregB + sigm(s1[0]) * tanhfast(s1[2]);
            cregA = cnA; cregB = cnB;
            float hA = sigm(s0[3]) * tanhfast(cnA);
            float hB = sigm(s1[3]) * tanhfast(cnB);
            hcur[c] = hA; hcur[c + 64] = hB;
            comb[t * H2 + dir * H1 + c]      = hA;   // plain stores
            comb[t * H2 + dir * H1 + c + 64] = hB;
        }
        __syncthreads();
    }
}

// ---------------------------------------------------------------------------
// Layer-2 LSTM: 4 active blocks (bid%8==0 -> XCD-clustered heuristic),
// 64 cells each. comb fully materialized -> prologue computes all gx
// upfront; recurrence has exactly ONE agent-scope wait per step (h-exchange).
// hg2 parity-double-buffered; correctness of the one-slot window follows
// from the step-t+2-needs-step-t+1-of-others dependency chain.
// ---------------------------------------------------------------------------
__global__ __launch_bounds__(1024, 1) void k_l2(
    const float* __restrict__ Whhl,
    const float* __restrict__ h0l, const float* __restrict__ c0l,
    const float* __restrict__ Wihl,
    const float* __restrict__ bihl, const float* __restrict__ bhhl,
    const float* __restrict__ comb,
    float* __restrict__ fb,        // [SEQ][H2]
    float* __restrict__ hg2,       // [2][H2] parity slots
    int* __restrict__ flags)       // flags[s*32], s=0..3
{
    const int bid = blockIdx.x;
    if (bid & 7) return;
    const int s   = bid >> 3;                 // 0..3, cells [s*64, s*64+64)
    const int tid = threadIdx.x;

    __shared__ __align__(16) float smem[12048];
    float* cs      = smem;                    // 5120
    float* hc2     = cs + 5120;               // 256
    float* bias2   = hc2 + 256;               // 256
    float* partial = bias2 + 256;             // 4*260 = 1040
    float* gxs     = partial + 1040;          // 256*21 = 5376

    const int cg = tid >> 8;                  // 0..3: cols [cg*64, cg*64+64)
    const int L  = tid & 255;                 // local gate row
    const int R  = (L >> 6) * H2 + s * 64 + (L & 63);

    for (int i = tid; i < SEQ * H2; i += 1024) cs[i] = comb[i];
    if (tid < 256) { bias2[tid] = bihl[R] + bhhl[R]; hc2[tid] = h0l[tid]; }
    float creg = (tid < 64) ? c0l[s * 64 + tid] : 0.0f;

    // ---- prologue: Wihl slice in regs, gxs[L][t] for all t ----
    float4 w[16];
    {
        const float4* p = (const float4*)(Wihl + (size_t)R * H2 + cg * 64);
#pragma unroll
        for (int j = 0; j < 16; ++j) { w[j] = p[j]; KEEPF4(w[j]); }
    }
    __syncthreads();
    for (int t = 0; t < SEQ; ++t) {
        const float4* cp = (const float4*)(cs + t * H2 + cg * 64);  // broadcast
        float a = 0.f;
#pragma unroll
        for (int j = 0; j < 16; ++j) {
            float4 v = cp[j];
            a += w[j].x * v.x + w[j].y * v.y + w[j].z * v.z + w[j].w * v.w;
        }
        partial[cg * 260 + L] = a;
        __syncthreads();
        if (tid < 256)
            gxs[tid * 21 + t] = bias2[tid] + partial[tid] + partial[260 + tid]
                              + partial[520 + tid] + partial[780 + tid];
        __syncthreads();
    }

    // ---- Whhl slice -> registers ----
    {
        const float4* p = (const float4*)(Whhl + (size_t)R * H2 + cg * 64);
#pragma unroll
        for (int j = 0; j < 16; ++j) { w[j] = p[j]; KEEPF4(w[j]); }
    }
    __syncthreads();

    // ---- recurrence: one exchange wait per step ----
    for (int t = 0; t < SEQ; ++t) {
        const float4* hp = (const float4*)(hc2 + cg * 64);          // broadcast
        float a = 0.f;
#pragma unroll
        for (int j = 0; j < 16; ++j) {
            float4 v = hp[j];
            a += w[j].x * v.x + w[j].y * v.y + w[j].z * v.z + w[j].w * v.w;
        }
        partial[cg * 260 + L] = a;
        __syncthreads();
        if (tid < 64) {
            // wave 0: finish own 64 cells, publish
            const int c = tid;
            float sg[4];
#pragma unroll
            for (int g = 0; g < 4; ++g) {
                float acc = gxs[(g * 64 + c) * 21 + t];
#pragma unroll
                for (int q = 0; q < 4; ++q)
                    acc += partial[q * 260 + g * 64 + c];
                sg[g] = acc;
            }
            float cn = sigm(sg[1]) * creg + sigm(sg[0]) * tanhfast(sg[2]);
            creg = cn;
            float hn = sigm(sg[3]) * tanhfast(cn);
            fb[t * H2 + s * 64 + c] = hn;     // plain store (next kernel reads)
            hc2[s * 64 + c] = hn;
            if (t + 1 < SEQ) {
                __hip_atomic_store(&hg2[(t & 1) * H2 + s * 64 + c], hn, RX, AG);
                if (tid == 0)
                    __hip_atomic_store(&flags[s * 32], t + 1, RL, AG);
            }
        } else if (tid >= 64 && tid < 112 && t + 1 < SEQ) {
            // wave 1 (48 lanes): pull the 3 remote shards' h (16 lanes each)
            const int l  = tid - 64;
            const int rs = (s + 1 + (l >> 4)) & 3;
            const int base = rs * 64 + (l & 15) * 4;
            while (__hip_atomic_load(&flags[rs * 32], AQ, AG) < t + 1)
                __builtin_amdgcn_s_sleep(1);
#pragma unroll
            for (int j = 0; j < 4; ++j)
                hc2[base + j] =
                    __hip_atomic_load(&hg2[(t & 1) * H2 + base + j], RX, AG);
        }
        __syncthreads();
    }
}

// ---------------------------------------------------------------------------
// Output GEMV, k-split x4: 4 lanes per class (64 cols each), shfl combine,
// LDS-bounced coalesced stores. 400K threads -> ~24 waves/CU latency hiding.
// ---------------------------------------------------------------------------
__global__ __launch_bounds__(256, 4) void k_out4(
    const float* __restrict__ Wlin, const float* __restrict__ blin,
    const float* __restrict__ fb, float* __restrict__ out)
{
    __shared__ __align__(16) float fbs[H2 * SEQ];   // [k][t], stride 20
    __shared__ float obuf[64 * 21];
    const int tid = threadIdx.x;
    for (int t = 0; t < SEQ; ++t) fbs[tid * SEQ + t] = fb[t * H2 + tid];
    __syncthreads();

    const int base = blockIdx.x * 64;
    const int c = tid >> 2, q = tid & 3;
    const int n = base + c;

    float acc[SEQ];
#pragma unroll
    for (int t = 0; t < SEQ; ++t) acc[t] = 0.f;

    if (n < NCLS) {
        const float* wp = Wlin + (size_t)n * H2 + q * 64;
        const float* fp = fbs + (q * 64) * SEQ;
        for (int k = 0; k < 64; k += 4) {
            float4 wv = *(const float4*)(wp + k);
            const float* f0 = fp + k * SEQ;
#pragma unroll
            for (int t = 0; t < SEQ; t += 4) {
                float4 a0 = *(const float4*)(f0 + t);
                float4 a1 = *(const float4*)(f0 + SEQ + t);
                float4 a2 = *(const float4*)(f0 + 2 * SEQ + t);
                float4 a3 = *(const float4*)(f0 + 3 * SEQ + t);
                acc[t]     += wv.x * a0.x + wv.y * a1.x + wv.z * a2.x + wv.w * a3.x;
                acc[t + 1] += wv.x * a0.y + wv.y * a1.y + wv.z * a2.y + wv.w * a3.y;
                acc[t + 2] += wv.x * a0.z + wv.y * a1.z + wv.z * a2.z + wv.w * a3.z;
                acc[t + 3] += wv.x * a0.w + wv.y * a1.w + wv.z * a2.w + wv.w * a3.w;
            }
        }
    }
#pragma unroll
    for (int t = 0; t < SEQ; ++t) {
        acc[t] += __shfl_xor(acc[t], 1);
        acc[t] += __shfl_xor(acc[t], 2);
    }
    if (q == 0) {
#pragma unroll
        for (int t = 0; t < SEQ; ++t) obuf[c * 21 + t] = acc[t];
    }
    __syncthreads();
    for (int i = tid; i < 64 * SEQ; i += 256) {
        const int t = i >> 6, cc = i & 63;
        const int n2 = base + cc;
        if (n2 < NCLS)
            out[(size_t)t * NCLS + n2] = obuf[cc * 21 + t] + blin[n2];
    }
}

// ---------------------------------------------------------------------------
extern "C" void kernel_launch(void* const* d_in, const int* in_sizes, int n_in,
                              void* d_out, int out_size, void* d_ws, size_t ws_size,
                              hipStream_t stream)
{
    const float* x    = (const float*)d_in[0];
    const float* h0f_ = (const float*)d_in[1];
    const float* c0f_ = (const float*)d_in[2];
    const float* h0b_ = (const float*)d_in[3];
    const float* c0b_ = (const float*)d_in[4];
    const float* h0l_ = (const float*)d_in[5];
    const float* c0l_ = (const float*)d_in[6];
    const float* WihF = (const float*)d_in[7];
    const float* WhhF = (const float*)d_in[8];
    const float* bihF = (const float*)d_in[9];
    const float* bhhF = (const float*)d_in[10];
    const float* WihB = (const float*)d_in[11];
    const float* WhhB = (const float*)d_in[12];
    const float* bihB = (const float*)d_in[13];
    const float* bhhB = (const float*)d_in[14];
    const float* Wihl = (const float*)d_in[15];
    const float* Whhl = (const float*)d_in[16];
    const float* bihl = (const float*)d_in[17];
    const float* bhhl = (const float*)d_in[18];
    const float* Wlin = (const float*)d_in[19];
    const float* blin = (const float*)d_in[20];

    char* ws = (char*)d_ws;
    int*   flags = (int*)ws;                     // 4 flags, 128-B apart
    float* hg2   = (float*)(ws + 2048);          // [2][256]
    float* comb  = (float*)(ws + 4096);          // [20][256]
    float* fb    = (float*)(ws + 24576);         // [20][256]

    hipMemsetAsync(flags, 0, 2048, stream);

    k_l1<<<2, 1024, 0, stream>>>(x, h0f_, c0f_, h0b_, c0b_,
                                 WihF, WhhF, bihF, bhhF,
                                 WihB, WhhB, bihB, bhhB, comb);
    k_l2<<<32, 1024, 0, stream>>>(Whhl, h0l_, c0l_,
                                  Wihl, bihl, bhhl,
                                  comb, fb, hg2, flags);
    k_out4<<<(NCLS + 63) / 64, 256, 0, stream>>>(Wlin, blin, fb, (float*)d_out);
}